// Round 12
// baseline (207.271 us; speedup 1.0000x reference)
//
#include <hip/hip_runtime.h>
#include <math.h>

#define BB 64
#define NN 8732
#define NV4 (NN / 4)  // 2183
#define CC 21
#define TB 64         // boxes per block = 1 wave
#define GX 137        // blocks per row = ceil(8732/64)
#define KAB 2048      // stream-probe blocks
#define REP 4         // probe repeat factor (amplifies dur above the 39us fills)

typedef unsigned int u32;
typedef __attribute__((address_space(1))) const u32 gu32;
typedef __attribute__((address_space(3))) u32 lu32;

static __device__ __forceinline__ unsigned f2u(float f) {
  unsigned u = __float_as_uint(f);
  return (u & 0x80000000u) ? ~u : (u | 0x80000000u);
}

#define GLDS(src, dstbase) \
  __builtin_amdgcn_global_load_lds((gu32*)(const u32*)(src), (lu32*)(u32*)(dstbase), 16, 0, 0)

// ---- PROBE A x4: grid-stride float4 streaming (m13 structure) on this data ----
__global__ __launch_bounds__(256) void kA_stream(
    const float4* __restrict__ a, long na, const float4* __restrict__ b, long nb,
    const float4* __restrict__ c, long nc, const float4* __restrict__ d, long nd,
    float* __restrict__ decoy) {
  const long t0 = (long)blockIdx.x * 256 + threadIdx.x;
  const long stride = (long)KAB * 256;
  float s = 0.f;
  for (int r = 0; r < REP; ++r) {  // +r rotates addresses: defeats load-CSE
    for (long i = t0 + r; i < na; i += stride) { float4 v = a[i]; s += v.x + v.y + v.z + v.w; }
    for (long i = t0 + r; i < nb; i += stride) { float4 v = b[i]; s += v.x + v.y + v.z + v.w; }
    for (long i = t0 + r; i < nc; i += stride) { float4 v = c[i]; s += v.x + v.y + v.z + v.w; }
    for (long i = t0 + r; i < nd; i += stride) { float4 v = d[i]; s += v.x + v.y + v.z + v.w; }
  }
  for (int o = 32; o > 0; o >>= 1) s += __shfl_down(s, o, 64);
  if ((threadIdx.x & 63) == 0) decoy[blockIdx.x * 4 + (threadIdx.x >> 6)] = s;
}

// ---- PROBE B x4: R10 staging structure (gload_lds DMA), trivial compute ----
__global__ __launch_bounds__(64) void kB_staged(
    const float* __restrict__ abd, const float* __restrict__ lbl,
    const float* __restrict__ pbd, const float* __restrict__ plog,
    float* __restrict__ decoy) {
  __shared__ __align__(16) float s_plog[TB * CC];
  __shared__ __align__(16) float s_lbl[TB * CC];
  __shared__ __align__(16) float4 s_ab[TB];
  __shared__ __align__(16) float4 s_pb[TB];

  const int b = blockIdx.y;
  const int base = blockIdx.x * TB;
  const int nbox = min(TB, NN - base);
  const int nf4 = (nbox * CC) >> 2;
  const int tid = threadIdx.x;
  const size_t rowbase = (size_t)b * NN;
  const float4* plog4 = reinterpret_cast<const float4*>(plog + (rowbase + base) * CC);
  const float4* lbl4 = reinterpret_cast<const float4*>(lbl + (rowbase + base) * CC);

  float s = 0.f;
  for (int r = 0; r < REP; ++r) {
#pragma unroll
    for (int it = 0; it < 6; ++it) {
      const int t = it * TB + tid;
      if (t < nf4) {
        GLDS(plog4 + t, (char*)s_plog + (size_t)it * TB * 16);
        GLDS(lbl4 + t, (char*)s_lbl + (size_t)it * TB * 16);
      }
    }
    if (tid < nbox) {
      GLDS(reinterpret_cast<const float4*>(abd) + rowbase + base + tid, (char*)s_ab);
      GLDS(reinterpret_cast<const float4*>(pbd) + rowbase + base + tid, (char*)s_pb);
    }
    asm volatile("s_waitcnt vmcnt(0)" ::: "memory");
    __builtin_amdgcn_sched_barrier(0);
    __syncthreads();
    if (tid < nbox) {
#pragma unroll
      for (int j = 0; j < CC; ++j) s += s_plog[tid * CC + j] + s_lbl[tid * CC + j];
      const float4 a = s_ab[tid], p = s_pb[tid];
      s += a.x + a.y + a.z + a.w + p.x + p.y + p.z + p.w;
      s *= 0.5f;  // keep per-rep dataflow live
    }
    __syncthreads();  // protect LDS before next rep's DMA overwrite
  }
  float sv = s;
  for (int o = 32; o > 0; o >>= 1) sv += __shfl_down(sv, o, 64);
  if (tid == 0) decoy[b * GX + blockIdx.x] = sv;
}

// ---- PROBE D x4: direct per-thread row loads, no LDS, full occupancy ----
__global__ __launch_bounds__(256) void kD_direct(
    const float* __restrict__ abd, const float* __restrict__ lbl,
    const float* __restrict__ pbd, const float* __restrict__ plog,
    float* __restrict__ decoy) {
  const int TOT = BB * NN;  // 558848 = 2183*256 exactly
  const int i0 = blockIdx.x * 256 + threadIdx.x;
  float s = 0.f;
  for (int r = 0; r < REP; ++r) {
    const int i = (i0 + r * 1237) % TOT;  // rotate: defeats CSE
    const float* pr = plog + (size_t)i * CC;
    const float* lr = lbl + (size_t)i * CC;
#pragma unroll
    for (int j = 0; j < CC; ++j) s += pr[j] + lr[j];
    const float4 a = reinterpret_cast<const float4*>(abd)[i];
    const float4 p = reinterpret_cast<const float4*>(pbd)[i];
    s += a.x + a.y + a.z + a.w + p.x + p.y + p.z + p.w;
  }
  for (int o = 32; o > 0; o >>= 1) s += __shfl_down(s, o, 64);
  if ((threadIdx.x & 63) == 0) decoy[blockIdx.x * 4 + (threadIdx.x >> 6)] = s;
}

// ---- kC: the real k1 (R10, unchanged) ----
__global__ __launch_bounds__(64) void k1_map(
    const float* __restrict__ abd, const float* __restrict__ lbl,
    const float* __restrict__ pbd, const float* __restrict__ plog,
    unsigned* __restrict__ keys, float* __restrict__ cep,
    float* __restrict__ pl, float* __restrict__ pc, int* __restrict__ pcnt) {
  __shared__ __align__(16) float s_plog[TB * CC];
  __shared__ __align__(16) float s_lbl[TB * CC];
  __shared__ __align__(16) float4 s_ab[TB];
  __shared__ __align__(16) float4 s_pb[TB];

  const int b = blockIdx.y;
  const int base = blockIdx.x * TB;
  const int nbox = min(TB, NN - base);
  const int nf4 = (nbox * CC) >> 2;
  const int tid = threadIdx.x;
  const size_t rowbase = (size_t)b * NN;

  const float4* plog4 = reinterpret_cast<const float4*>(plog + (rowbase + base) * CC);
  const float4* lbl4 = reinterpret_cast<const float4*>(lbl + (rowbase + base) * CC);
#pragma unroll
  for (int it = 0; it < 6; ++it) {
    const int t = it * TB + tid;
    if (t < nf4) {
      GLDS(plog4 + t, (char*)s_plog + (size_t)it * TB * 16);
      GLDS(lbl4 + t, (char*)s_lbl + (size_t)it * TB * 16);
    }
  }
  if (tid < nbox) {
    GLDS(reinterpret_cast<const float4*>(abd) + rowbase + base + tid, (char*)s_ab);
    GLDS(reinterpret_cast<const float4*>(pbd) + rowbase + base + tid, (char*)s_pb);
  }
  asm volatile("s_waitcnt vmcnt(0)" ::: "memory");
  __builtin_amdgcn_sched_barrier(0);
  __syncthreads();

  float loc = 0.f, pconf = 0.f;
  int isPos = 0;
  if (tid < nbox) {
    const size_t idx = rowbase + base + tid;
    const float4 a = s_ab[tid];
    const float4 p = s_pb[tid];
    isPos = (a.x != 0.f) || (a.y != 0.f) || (a.z != 0.f) || (a.w != 0.f);

    int cls = 0;
#pragma unroll
    for (int j = 0; j < CC; ++j)
      cls = (s_lbl[tid * CC + j] != 0.f) ? j : cls;

    float pv[CC];
    float m = -INFINITY, ssum = 0.f, tdot = 0.f;
#pragma unroll
    for (int j = 0; j < CC; ++j) {
      const float v = s_plog[tid * CC + j];
      pv[j] = v;
      m = fmaxf(m, v);
      ssum += v;
      tdot = (j == cls) ? v : tdot;
    }
    float es = 0.f;
#pragma unroll
    for (int j = 0; j < CC; ++j) es += expf(pv[j] - m);
    const float pt = tdot / ssum;
    const float ptc = fminf(fmaxf(pt, 1e-7f), 1.0f - 1e-7f);
    const float cp = -logf(ptc);
    const float cel = (m + logf(es)) - tdot;
    keys[idx] = isPos ? 0u : f2u(cel);
    cep[idx] = cp;
    pconf = isPos ? cp : 0.f;
    const float dx = p.x - a.x, dy = p.y - a.y, dz = p.z - a.z, dw = p.w - a.w;
    const float axv = fabsf(dx), ayv = fabsf(dy), azv = fabsf(dz), awv = fabsf(dw);
    const float h = (axv <= 1.f ? 0.5f * dx * dx : axv - 0.5f)
                  + (ayv <= 1.f ? 0.5f * dy * dy : ayv - 0.5f)
                  + (azv <= 1.f ? 0.5f * dz * dz : azv - 0.5f)
                  + (awv <= 1.f ? 0.5f * dw * dw : awv - 0.5f);
    loc = isPos ? h * 0.25f : 0.f;
  }
  float lvv = loc, pcf = pconf;
  int pctr = isPos;
  for (int off = 32; off > 0; off >>= 1) {
    lvv += __shfl_down(lvv, off, 64);
    pcf += __shfl_down(pcf, off, 64);
    pctr += __shfl_down(pctr, off, 64);
  }
  if (tid == 0) {
    const int bi = b * GX + blockIdx.x;
    pl[bi] = lvv;
    pc[bi] = pcf;
    pcnt[bi] = pctr;
  }
}

// Kernel 2: per-row partial-reduce + exact radix-select (unchanged).
#define K2T 1024
#define K2W 16

__global__ __launch_bounds__(K2T) void k2_select(
    const unsigned* __restrict__ keys, const float* __restrict__ cep,
    const float* __restrict__ pl, const float* __restrict__ pc,
    const int* __restrict__ pcnt,
    double* __restrict__ row_loc, double* __restrict__ row_conf,
    int* __restrict__ row_pos) {
  __shared__ unsigned hist[2048];
  __shared__ unsigned wsum[K2W];
  __shared__ unsigned bc[2];
  __shared__ unsigned wtot[K2W];
  __shared__ double s_d[K2W];
  __shared__ double s_rl, s_rc;
  __shared__ int s_pos;
  const int b = blockIdx.x;
  const int tid = threadIdx.x;
  const int lane = tid & 63, wv = tid >> 6;

  if (wv == 0) {
    float a = 0.f, c = 0.f;
    int p = 0;
    for (int i = lane; i < GX; i += 64) {
      a += pl[b * GX + i];
      c += pc[b * GX + i];
      p += pcnt[b * GX + i];
    }
    for (int off = 32; off > 0; off >>= 1) {
      a += __shfl_down(a, off, 64);
      c += __shfl_down(c, off, 64);
      p += __shfl_down(p, off, 64);
    }
    if (lane == 0) { s_rl = (double)a; s_rc = (double)c; s_pos = p; }
  }
  __syncthreads();
  const int pos = s_pos;
  unsigned k = (unsigned)(pos * 3);
  const unsigned negs = (unsigned)(NN - pos);
  if (k > negs) k = negs;

  double neg_total = 0.0;
  if (k > 0) {
    const unsigned* rk = keys + (size_t)b * NN;
    const uint4* rk4 = reinterpret_cast<const uint4*>(rk);
    unsigned want = k;
    unsigned prefix = 0;
    for (int pass = 0; pass < 3; ++pass) {
      const int nb = (pass == 2) ? 1024 : 2048;
      const int shift = (pass == 0) ? 21 : (pass == 1) ? 10 : 0;
      for (int i = tid; i < nb; i += K2T) hist[i] = 0;
      __syncthreads();
      if (pass == 0) {
        for (int t = tid; t < NV4; t += K2T) {
          uint4 v = rk4[t];
          atomicAdd(&hist[v.x >> 21], 1u);
          atomicAdd(&hist[v.y >> 21], 1u);
          atomicAdd(&hist[v.z >> 21], 1u);
          atomicAdd(&hist[v.w >> 21], 1u);
        }
      } else {
        const unsigned pshift = (pass == 1) ? 21u : 10u;
        const unsigned msk = (unsigned)(nb - 1);
        for (int t = tid; t < NV4; t += K2T) {
          uint4 v = rk4[t];
          if ((v.x >> pshift) == prefix) atomicAdd(&hist[(v.x >> shift) & msk], 1u);
          if ((v.y >> pshift) == prefix) atomicAdd(&hist[(v.y >> shift) & msk], 1u);
          if ((v.z >> pshift) == prefix) atomicAdd(&hist[(v.z >> shift) & msk], 1u);
          if ((v.w >> pshift) == prefix) atomicAdd(&hist[(v.w >> shift) & msk], 1u);
        }
      }
      __syncthreads();
      const int PR = nb / K2T;
      unsigned v0, v1 = 0, ls;
      if (PR == 2) {
        v0 = hist[nb - 1 - (tid * 2)];
        v1 = hist[nb - 1 - (tid * 2 + 1)];
        ls = v0 + v1;
      } else {
        v0 = hist[nb - 1 - tid];
        ls = v0;
      }
      unsigned x = ls;
#pragma unroll
      for (int off = 1; off < 64; off <<= 1) {
        unsigned y = __shfl_up(x, off, 64);
        if (lane >= off) x += y;
      }
      if (lane == 63) wsum[wv] = x;
      __syncthreads();
      if (wv == 0 && lane < K2W) {
        unsigned wx = wsum[lane];
#pragma unroll
        for (int off = 1; off < K2W; off <<= 1) {
          unsigned wy = __shfl_up(wx, off, K2W);
          if ((lane & (K2W - 1)) >= off) wx += wy;
        }
        wsum[lane] = wx;
      }
      __syncthreads();
      const unsigned woff = (wv == 0) ? 0u : wsum[wv - 1];
      const unsigned pinc = woff + x;
      if (PR == 2) {
        const unsigned p0 = pinc - ls + v0;
        const unsigned p1 = pinc;
        if (v0 > 0 && p0 >= want && p0 - v0 < want) { bc[0] = (unsigned)(nb - 1 - tid * 2); bc[1] = want - (p0 - v0); }
        if (v1 > 0 && p1 >= want && p1 - v1 < want) { bc[0] = (unsigned)(nb - 1 - (tid * 2 + 1)); bc[1] = want - (p1 - v1); }
      } else {
        if (v0 > 0 && pinc >= want && pinc - v0 < want) { bc[0] = (unsigned)(nb - 1 - tid); bc[1] = want - (pinc - v0); }
      }
      __syncthreads();
      const unsigned d = bc[0];
      want = bc[1];
      prefix = (pass == 0) ? d : ((prefix << ((pass == 1) ? 11 : 10)) | d);
      __syncthreads();
    }
    const unsigned tau = prefix;
    const unsigned neq = want;

    const float* rc = cep + (size_t)b * NN;
    double mysum = 0.0;
    unsigned bbase = 0;
    for (int start = 0; start < NN; start += K2T) {
      const int i = start + tid;
      const unsigned key = (i < NN) ? rk[i] : 0u;
      const bool gt = (i < NN) && (key > tau);
      const bool eq = (i < NN) && (key == tau);
      if (gt) mysum += (double)rc[i];
      const unsigned long long mb = __ballot(eq);
      if (lane == 0) wtot[wv] = (unsigned)__popcll(mb);
      __syncthreads();
      unsigned wpref = 0, tot = 0;
#pragma unroll
      for (int w = 0; w < K2W; ++w) {
        const unsigned c = wtot[w];
        wpref += (w < wv) ? c : 0u;
        tot += c;
      }
      if (eq) {
        const unsigned lanepref = (unsigned)__popcll(mb & ((1ull << lane) - 1ull));
        if (bbase + wpref + lanepref < neq) mysum += (double)rc[i];
      }
      bbase += tot;
      __syncthreads();
    }
    for (int off = 32; off > 0; off >>= 1) mysum += __shfl_down(mysum, off, 64);
    if (lane == 0) s_d[wv] = mysum;
    __syncthreads();
    if (tid == 0) {
#pragma unroll
      for (int w = 0; w < K2W; ++w) neg_total += s_d[w];
    }
  }
  if (tid == 0) {
    row_loc[b] = s_rl;
    row_conf[b] = s_rc + neg_total;
    row_pos[b] = pos;
  }
}

// Kernel 3: reduce 64 rows, finalize the two scalars.
__global__ void k3_final(const double* __restrict__ row_loc,
                         const double* __restrict__ row_conf,
                         const int* __restrict__ row_pos,
                         float* __restrict__ out) {
  const int lane = threadIdx.x;
  double l = row_loc[lane], c = row_conf[lane];
  int p = row_pos[lane];
  for (int off = 32; off > 0; off >>= 1) {
    l += __shfl_down(l, off, 64);
    c += __shfl_down(c, off, 64);
    p += __shfl_down(p, off, 64);
  }
  if (lane == 0) {
    const double tot = (p > 0) ? (double)p : 1.0;
    out[0] = (float)(l / tot);
    out[1] = (float)(c / tot);
  }
}

extern "C" void kernel_launch(void* const* d_in, const int* in_sizes, int n_in,
                              void* d_out, int out_size, void* d_ws, size_t ws_size,
                              hipStream_t stream) {
  const float* abd = (const float*)d_in[0];
  const float* lbl = (const float*)d_in[1];
  const float* pbd = (const float*)d_in[2];
  const float* plog = (const float*)d_in[3];

  char* ws = (char*)d_ws;
  float* pl = (float*)(ws + 0);               // [8768]
  float* pc = (float*)(ws + 36864);           // [8768]
  int* pcnt = (int*)(ws + 73728);             // [8768]
  double* row_loc = (double*)(ws + 110592);   // [64]
  double* row_conf = (double*)(ws + 111104);  // [64]
  int* row_pos = (int*)(ws + 111616);         // [64]
  unsigned* keys = (unsigned*)(ws + 112128);  // [B*N]
  float* cep = (float*)(ws + 2347520);        // [B*N]
  float* decoyA = (float*)(ws + 4582912);     // [8192]
  float* decoyB = (float*)(ws + 4615680);     // [8768]
  float* decoyD = (float*)(ws + 4650752);     // [8732]

  const long nlab4 = (long)BB * NN * CC / 4;  // 2,933,952
  const long nbox4 = (long)BB * NN;           // 558,848

  dim3 g1(GX, BB);
  // Ablation probes (decoy outputs only; kC rewrites keys/cep afterwards)
  kA_stream<<<KAB, 256, 0, stream>>>(
      reinterpret_cast<const float4*>(plog), nlab4,
      reinterpret_cast<const float4*>(lbl), nlab4,
      reinterpret_cast<const float4*>(abd), nbox4,
      reinterpret_cast<const float4*>(pbd), nbox4, decoyA);
  kB_staged<<<g1, TB, 0, stream>>>(abd, lbl, pbd, plog, decoyB);
  kD_direct<<<2183, 256, 0, stream>>>(abd, lbl, pbd, plog, decoyD);
  // Real pipeline
  k1_map<<<g1, TB, 0, stream>>>(abd, lbl, pbd, plog, keys, cep, pl, pc, pcnt);
  k2_select<<<BB, K2T, 0, stream>>>(keys, cep, pl, pc, pcnt, row_loc, row_conf, row_pos);
  k3_final<<<1, 64, 0, stream>>>(row_loc, row_conf, row_pos, (float*)d_out);
}

// Round 13
// 40.983 us; speedup vs baseline: 5.0575x; 5.0575x over previous
//
#include <hip/hip_runtime.h>
#include <math.h>

#define BB 64
#define NN 8732
#define NV4 (NN / 4)  // 2183
#define CC 21
#define TB 256        // boxes per k1 block
#define GX 35         // k1 blocks per row = ceil(8732/256)

// Monotonic float->uint mapping (total order)
static __device__ __forceinline__ unsigned f2u(float f) {
  unsigned u = __float_as_uint(f);
  return (u & 0x80000000u) ? ~u : (u | 0x80000000u);
}

// Kernel 1: direct per-thread map (R2 structure) + atomic-free partials
// (R4 fix). R12 ablation: streaming this data hits 5.7 TB/s logical, and
// the direct-load probe (kD) swept in <=15us/rep — the 39-44us plateau was
// the LDS-staging+barrier+3-waves/SIMD structure (Occ 25%), kept alive
// since R3 only because it was introduced before R4 removed the atomic
// serializer that had made R2's direct form look slow. No LDS staging, no
// barriers, no vmcnt drain: occupancy and TLP hide the strided loads.
__global__ __launch_bounds__(256) void k1_map(
    const float* __restrict__ abd, const float* __restrict__ lbl,
    const float* __restrict__ pbd, const float* __restrict__ plog,
    unsigned* __restrict__ keys, float* __restrict__ cep,
    float* __restrict__ pl, float* __restrict__ pc, int* __restrict__ pcnt) {
  __shared__ float s_l[4], s_p[4];
  __shared__ int s_c[4];

  const int b = blockIdx.y;
  const int n = blockIdx.x * TB + threadIdx.x;
  const int tid = threadIdx.x;
  const bool valid = n < NN;
  float loc = 0.f, pconf = 0.f;
  int isPos = 0;
  if (valid) {
    const size_t idx = (size_t)b * NN + n;
    const float4 a = reinterpret_cast<const float4*>(abd)[idx];
    const float4 p = reinterpret_cast<const float4*>(pbd)[idx];
    isPos = (a.x != 0.f) || (a.y != 0.f) || (a.z != 0.f) || (a.w != 0.f);

    const float* pr = plog + idx * CC;
    const float* lr = lbl + idx * CC;
    float pv[CC];
    float m = -INFINITY, ssum = 0.f, tdot = 0.f;
#pragma unroll
    for (int j = 0; j < CC; ++j) {
      const float v = pr[j];
      pv[j] = v;
      m = fmaxf(m, v);
      ssum += v;
    }
    float es = 0.f;
#pragma unroll
    for (int j = 0; j < CC; ++j) {
      es += expf(pv[j] - m);
      tdot = fmaf(lr[j], pv[j], tdot);  // labels exact one-hot
    }
    const float pt = tdot / ssum;
    const float ptc = fminf(fmaxf(pt, 1e-7f), 1.0f - 1e-7f);
    const float cp = -logf(ptc);
    const float cel = (m + logf(es)) - tdot;  // mining key (CE from logits)
    keys[idx] = isPos ? 0u : f2u(cel);
    cep[idx] = cp;
    pconf = isPos ? cp : 0.f;
    const float dx = p.x - a.x, dy = p.y - a.y, dz = p.z - a.z, dw = p.w - a.w;
    const float axv = fabsf(dx), ayv = fabsf(dy), azv = fabsf(dz), awv = fabsf(dw);
    const float h = (axv <= 1.f ? 0.5f * dx * dx : axv - 0.5f)
                  + (ayv <= 1.f ? 0.5f * dy * dy : ayv - 0.5f)
                  + (azv <= 1.f ? 0.5f * dz * dz : azv - 0.5f)
                  + (awv <= 1.f ? 0.5f * dw * dw : awv - 0.5f);
    loc = isPos ? h * 0.25f : 0.f;
  }
  float lvv = loc, pcf = pconf;
  int pctr = isPos;
  for (int off = 32; off > 0; off >>= 1) {
    lvv += __shfl_down(lvv, off, 64);
    pcf += __shfl_down(pcf, off, 64);
    pctr += __shfl_down(pctr, off, 64);
  }
  const int lane = tid & 63, wv = tid >> 6;
  if (lane == 0) { s_l[wv] = lvv; s_p[wv] = pcf; s_c[wv] = pctr; }
  __syncthreads();
  if (tid == 0) {
    const int bi = b * GX + blockIdx.x;
    pl[bi] = s_l[0] + s_l[1] + s_l[2] + s_l[3];
    pc[bi] = s_p[0] + s_p[1] + s_p[2] + s_p[3];
    pcnt[bi] = s_c[0] + s_c[1] + s_c[2] + s_c[3];
  }
}

// Kernel 2: per-row partial-reduce + exact radix-select (R4 core, GX=35).
#define K2T 1024
#define K2W 16

__global__ __launch_bounds__(K2T) void k2_select(
    const unsigned* __restrict__ keys, const float* __restrict__ cep,
    const float* __restrict__ pl, const float* __restrict__ pc,
    const int* __restrict__ pcnt,
    double* __restrict__ row_loc, double* __restrict__ row_conf,
    int* __restrict__ row_pos) {
  __shared__ unsigned hist[2048];
  __shared__ unsigned wsum[K2W];
  __shared__ unsigned bc[2];
  __shared__ unsigned wtot[K2W];
  __shared__ double s_d[K2W];
  __shared__ double s_rl, s_rc;
  __shared__ int s_pos;
  const int b = blockIdx.x;
  const int tid = threadIdx.x;
  const int lane = tid & 63, wv = tid >> 6;

  if (wv == 0) {
    float a = 0.f, c = 0.f;
    int p = 0;
    if (lane < GX) {
      a = pl[b * GX + lane];
      c = pc[b * GX + lane];
      p = pcnt[b * GX + lane];
    }
    for (int off = 32; off > 0; off >>= 1) {
      a += __shfl_down(a, off, 64);
      c += __shfl_down(c, off, 64);
      p += __shfl_down(p, off, 64);
    }
    if (lane == 0) { s_rl = (double)a; s_rc = (double)c; s_pos = p; }
  }
  __syncthreads();
  const int pos = s_pos;
  unsigned k = (unsigned)(pos * 3);
  const unsigned negs = (unsigned)(NN - pos);
  if (k > negs) k = negs;

  double neg_total = 0.0;
  if (k > 0) {  // block-uniform branch
    const unsigned* rk = keys + (size_t)b * NN;
    const uint4* rk4 = reinterpret_cast<const uint4*>(rk);
    unsigned want = k;
    unsigned prefix = 0;
    for (int pass = 0; pass < 3; ++pass) {
      const int nb = (pass == 2) ? 1024 : 2048;
      const int shift = (pass == 0) ? 21 : (pass == 1) ? 10 : 0;
      for (int i = tid; i < nb; i += K2T) hist[i] = 0;
      __syncthreads();
      if (pass == 0) {
        for (int t = tid; t < NV4; t += K2T) {
          uint4 v = rk4[t];
          atomicAdd(&hist[v.x >> 21], 1u);
          atomicAdd(&hist[v.y >> 21], 1u);
          atomicAdd(&hist[v.z >> 21], 1u);
          atomicAdd(&hist[v.w >> 21], 1u);
        }
      } else {
        const unsigned pshift = (pass == 1) ? 21u : 10u;
        const unsigned msk = (unsigned)(nb - 1);
        for (int t = tid; t < NV4; t += K2T) {
          uint4 v = rk4[t];
          if ((v.x >> pshift) == prefix) atomicAdd(&hist[(v.x >> shift) & msk], 1u);
          if ((v.y >> pshift) == prefix) atomicAdd(&hist[(v.y >> shift) & msk], 1u);
          if ((v.z >> pshift) == prefix) atomicAdd(&hist[(v.z >> shift) & msk], 1u);
          if ((v.w >> pshift) == prefix) atomicAdd(&hist[(v.w >> shift) & msk], 1u);
        }
      }
      __syncthreads();
      const int PR = nb / K2T;
      unsigned v0, v1 = 0, ls;
      if (PR == 2) {
        v0 = hist[nb - 1 - (tid * 2)];
        v1 = hist[nb - 1 - (tid * 2 + 1)];
        ls = v0 + v1;
      } else {
        v0 = hist[nb - 1 - tid];
        ls = v0;
      }
      unsigned x = ls;
#pragma unroll
      for (int off = 1; off < 64; off <<= 1) {
        unsigned y = __shfl_up(x, off, 64);
        if (lane >= off) x += y;
      }
      if (lane == 63) wsum[wv] = x;
      __syncthreads();
      if (wv == 0 && lane < K2W) {
        unsigned wx = wsum[lane];
#pragma unroll
        for (int off = 1; off < K2W; off <<= 1) {
          unsigned wy = __shfl_up(wx, off, K2W);
          if ((lane & (K2W - 1)) >= off) wx += wy;
        }
        wsum[lane] = wx;
      }
      __syncthreads();
      const unsigned woff = (wv == 0) ? 0u : wsum[wv - 1];
      const unsigned pinc = woff + x;
      if (PR == 2) {
        const unsigned p0 = pinc - ls + v0;
        const unsigned p1 = pinc;
        if (v0 > 0 && p0 >= want && p0 - v0 < want) { bc[0] = (unsigned)(nb - 1 - tid * 2); bc[1] = want - (p0 - v0); }
        if (v1 > 0 && p1 >= want && p1 - v1 < want) { bc[0] = (unsigned)(nb - 1 - (tid * 2 + 1)); bc[1] = want - (p1 - v1); }
      } else {
        if (v0 > 0 && pinc >= want && pinc - v0 < want) { bc[0] = (unsigned)(nb - 1 - tid); bc[1] = want - (pinc - v0); }
      }
      __syncthreads();
      const unsigned d = bc[0];
      want = bc[1];
      prefix = (pass == 0) ? d : ((prefix << ((pass == 1) ? 11 : 10)) | d);
      __syncthreads();
    }
    const unsigned tau = prefix;
    const unsigned neq = want;

    const float* rc = cep + (size_t)b * NN;
    double mysum = 0.0;
    unsigned bbase = 0;
    for (int start = 0; start < NN; start += K2T) {
      const int i = start + tid;
      const unsigned key = (i < NN) ? rk[i] : 0u;
      const bool gt = (i < NN) && (key > tau);
      const bool eq = (i < NN) && (key == tau);
      if (gt) mysum += (double)rc[i];
      const unsigned long long mb = __ballot(eq);
      if (lane == 0) wtot[wv] = (unsigned)__popcll(mb);
      __syncthreads();
      unsigned wpref = 0, tot = 0;
#pragma unroll
      for (int w = 0; w < K2W; ++w) {
        const unsigned c = wtot[w];
        wpref += (w < wv) ? c : 0u;
        tot += c;
      }
      if (eq) {
        const unsigned lanepref = (unsigned)__popcll(mb & ((1ull << lane) - 1ull));
        if (bbase + wpref + lanepref < neq) mysum += (double)rc[i];
      }
      bbase += tot;
      __syncthreads();
    }
    for (int off = 32; off > 0; off >>= 1) mysum += __shfl_down(mysum, off, 64);
    if (lane == 0) s_d[wv] = mysum;
    __syncthreads();
    if (tid == 0) {
#pragma unroll
      for (int w = 0; w < K2W; ++w) neg_total += s_d[w];
    }
  }
  if (tid == 0) {
    row_loc[b] = s_rl;
    row_conf[b] = s_rc + neg_total;
    row_pos[b] = pos;
  }
}

// Kernel 3: reduce 64 rows, finalize the two scalars.
__global__ void k3_final(const double* __restrict__ row_loc,
                         const double* __restrict__ row_conf,
                         const int* __restrict__ row_pos,
                         float* __restrict__ out) {
  const int lane = threadIdx.x;  // 64 threads
  double l = row_loc[lane], c = row_conf[lane];
  int p = row_pos[lane];
  for (int off = 32; off > 0; off >>= 1) {
    l += __shfl_down(l, off, 64);
    c += __shfl_down(c, off, 64);
    p += __shfl_down(p, off, 64);
  }
  if (lane == 0) {
    const double tot = (p > 0) ? (double)p : 1.0;
    out[0] = (float)(l / tot);
    out[1] = (float)(c / tot);
  }
}

extern "C" void kernel_launch(void* const* d_in, const int* in_sizes, int n_in,
                              void* d_out, int out_size, void* d_ws, size_t ws_size,
                              hipStream_t stream) {
  const float* abd = (const float*)d_in[0];
  const float* lbl = (const float*)d_in[1];
  const float* pbd = (const float*)d_in[2];
  const float* plog = (const float*)d_in[3];

  char* ws = (char*)d_ws;
  float* pl = (float*)(ws + 0);              // [BB*GX] = 2240
  float* pc = (float*)(ws + 8960);           // [2240]
  int* pcnt = (int*)(ws + 17920);            // [2240]
  double* row_loc = (double*)(ws + 26880);   // [64]
  double* row_conf = (double*)(ws + 27392);  // [64]
  int* row_pos = (int*)(ws + 27904);         // [64]
  unsigned* keys = (unsigned*)(ws + 28160);  // [B*N], 16B-aligned
  float* cep = (float*)(ws + 28160 + (size_t)BB * NN * sizeof(unsigned));

  // All scratch is written unconditionally before being read -> no memset.
  dim3 g1(GX, BB);
  k1_map<<<g1, TB, 0, stream>>>(abd, lbl, pbd, plog, keys, cep, pl, pc, pcnt);
  k2_select<<<BB, K2T, 0, stream>>>(keys, cep, pl, pc, pcnt, row_loc, row_conf, row_pos);
  k3_final<<<1, 64, 0, stream>>>(row_loc, row_conf, row_pos, (float*)d_out);
}